// Round 9
// baseline (216.542 us; speedup 1.0000x reference)
//
#include <hip/hip_runtime.h>
#include <hip/hip_fp16.h>

typedef unsigned int u32;
typedef unsigned short u16;
typedef int i32x4 __attribute__((ext_vector_type(4)));
typedef float f32x4 __attribute__((ext_vector_type(4)));

#define OUT_F 8192
#define IN_F 8192
#define TOKENS 256
#define N_GROUPS 524288
#define SPLITK 4
#define KSPAN (IN_F / SPLITK)   // 2048 k per split
#define KT (KSPAN / 64)         // 32 K-slices of 64

// workspace layout
#define XQ_OFF 0                                         // x int8, 2 MiB
#define T_OFF ((size_t)TOKENS * IN_F)                    // lora t [256][16] f32, 16 KiB
#define SX_OFF (T_OFF + 16384)                           // x scales [2][256] f32
#define NF_OFF (SX_OFF + 2048)                           // norms f16 transposed [64][8192], 1 MiB
#define PART_OFF (NF_OFF + (size_t)N_GROUPS * 2)
#define PART_BYTES ((size_t)SPLITK * TOKENS * OUT_F * 4) // 32 MiB
#define WS_NEED (PART_OFF + PART_BYTES)

// code byte (2-bit codes q0..q3) -> u32 of 4 int8 codes 2q-3 (carry-free,
// verified R8: even/odd fields spread separately, disjoint bit ranges).
__device__ __forceinline__ u32 unpack4(u32 b) {
  u32 e = ((b & 0x33u) * 0x2002u) & 0x00060006u;   // 2*q0 @ byte0, 2*q2 @ byte2
  u32 o = ((b & 0xCCu) * 0x80080u) & 0x06000600u;  // 2*q1 @ byte1, 2*q3 @ byte3
  return ((e | o) + 0x7D7D7D7Du) ^ 0x80808080u;    // per byte: 2q-3 as int8
}

// ---------------------------------------------------------------------------
// prep: blocks [0,512): norm dtype auto-detect (f16/bf16/f32 vote) -> f16,
//   transposed to nf[g][n] (g = k/128) for coalesced per-group loads in gemm.
// blocks [512,1024): per (token m, k-half): absmax-quantize x -> int8 xq + sx.
// blocks [1024,1088): lora t-partials per 128-k chunk: la read ONCE total
//   (R8's layout re-read la 512x = ~11M VMEM instr); uniform-address la loads
//   broadcast from L1; atomicAdd into 16 KB t (zeroed by host memset).
// ---------------------------------------------------------------------------
__global__ __launch_bounds__(256) void prep(const void* __restrict__ wn,
                                            __half* __restrict__ nf,
                                            const float* __restrict__ x,
                                            const float* __restrict__ la,
                                            signed char* __restrict__ xq,
                                            float* __restrict__ sx,
                                            float* __restrict__ t) {
  int tid = threadIdx.x;
  if (blockIdx.x < 512) {
    __shared__ int votes[3];
    __shared__ u16 tile[64][17];
    if (tid < 3) votes[tid] = 0;
    __syncthreads();
    const u16* pu = (const u16*)wn;
    const u32* pw = (const u32*)wn;
    int v16 = 0, vbf = 0, vf = 0;
    for (int i = tid; i < 2048; i += 256) {
      u16 u = pu[i];
      float h = __half2float(__builtin_bit_cast(__half, u));
      float b = __builtin_bit_cast(float, ((u32)u) << 16);
      if (h > 0.008f && h < 1.002f) v16++;
      if (b > 0.008f && b < 1.002f) vbf++;
    }
    for (int i = tid; i < 1024; i += 256) {
      float f = __builtin_bit_cast(float, pw[i]);
      if (f > 0.008f && f < 1.002f) vf++;
    }
    atomicAdd(&votes[0], v16);
    atomicAdd(&votes[1], vbf);
    atomicAdd(&votes[2], vf);
    __syncthreads();
    int a16 = votes[0], abf = votes[1], af32 = 2 * votes[2];
    int mode = (a16 >= abf && a16 >= af32) ? 0 : (abf >= af32 ? 1 : 2);
    int nb = blockIdx.x * 16;  // n in [nb,nb+16), g in [0,64); flat = n*64+g
#pragma unroll
    for (int i = 0; i < 4; ++i) {
      int idx = i * 256 + tid;
      int g = idx & 63, nl = idx >> 6;
      int flat = (nb + nl) * 64 + g;
      float v;
      if (mode == 0) v = __half2float(((const __half*)wn)[flat]);
      else if (mode == 1) v = __builtin_bit_cast(float, ((u32)((const u16*)wn)[flat]) << 16);
      else v = ((const float*)wn)[flat];
      tile[g][nl] = __builtin_bit_cast(u16, __float2half(v));
    }
    __syncthreads();
#pragma unroll
    for (int i = 0; i < 4; ++i) {
      int idx = i * 256 + tid;
      int go = idx >> 4, no = idx & 15;
      ((u16*)nf)[(size_t)go * 8192 + nb + no] = tile[go][no];
    }
    return;
  }
  if (blockIdx.x < 1024) {  // x absmax-quant per (m, half)
    int b2 = blockIdx.x - 512;
    int m = b2 & 255;
    int half = b2 >> 8;
    const float4* xr = (const float4*)(x + (size_t)m * IN_F);
    float4 xv[4];
    float am = 0.f;
#pragma unroll
    for (int it = 0; it < 4; ++it) {
      xv[it] = xr[half * 1024 + it * 256 + tid];
      am = fmaxf(am, fmaxf(fmaxf(fabsf(xv[it].x), fabsf(xv[it].y)),
                           fmaxf(fabsf(xv[it].z), fabsf(xv[it].w))));
    }
#pragma unroll
    for (int d = 32; d > 0; d >>= 1) am = fmaxf(am, __shfl_xor(am, d));
    __shared__ float amS[4];
    int wave = tid >> 6;
    if ((tid & 63) == 0) amS[wave] = am;
    __syncthreads();
    am = fmaxf(fmaxf(amS[0], amS[1]), fmaxf(amS[2], amS[3]));
    float inv = (am > 1e-20f) ? 127.f / am : 0.f;
    u32* xqw = (u32*)(xq + (size_t)m * IN_F);
#pragma unroll
    for (int it = 0; it < 4; ++it) {
      int k4 = half * 1024 + it * 256 + tid;
      int q0 = (int)rintf(xv[it].x * inv);
      int q1 = (int)rintf(xv[it].y * inv);
      int q2 = (int)rintf(xv[it].z * inv);
      int q3 = (int)rintf(xv[it].w * inv);
      xqw[k4] = (q0 & 255) | ((q1 & 255) << 8) | ((q2 & 255) << 16) | ((q3 & 255) << 24);
    }
    if (tid == 0) sx[half * 256 + m] = am / 127.f;
    return;
  }
  // lora t-partials: chunk c covers k in [c*128, c*128+128); thread = token m
  int c = blockIdx.x - 1024;
  int k0 = c * 128;
  int m = tid;
  const float4* xr = (const float4*)(x + (size_t)m * IN_F + k0);
  float s[16];
#pragma unroll
  for (int r = 0; r < 16; ++r) s[r] = 0.f;
  for (int jj = 0; jj < 32; ++jj) {
    float4 xv = xr[jj];
#pragma unroll
    for (int r = 0; r < 16; ++r) {
      float4 lv = *(const float4*)(la + (size_t)r * IN_F + k0 + jj * 4);  // uniform -> L1 broadcast
      s[r] += xv.x * lv.x + xv.y * lv.y + xv.z * lv.z + xv.w * lv.w;
    }
  }
#pragma unroll
  for (int r = 0; r < 16; ++r) atomicAdd(&t[(size_t)m * 16 + r], s[r]);
}

// ---------------------------------------------------------------------------
// prep2 (fallback path only): d_out = bias + lora (atomic reduction target).
// ---------------------------------------------------------------------------
__global__ __launch_bounds__(256) void prep2(const float* __restrict__ t,
                                             const float* __restrict__ lb,
                                             const float* __restrict__ bias,
                                             float* __restrict__ out) {
  __shared__ float tS[16 * 16];
  int tid = threadIdx.x;
  int n = blockIdx.x * 256 + tid;
  int mbase = blockIdx.y * 16;
  if (tid < 64) ((float4*)tS)[tid] = ((const float4*)(t + (size_t)mbase * 16))[tid];
  const float4* lbp = (const float4*)(lb + (size_t)n * 16);
  float4 b0 = lbp[0], b1 = lbp[1], b2 = lbp[2], b3 = lbp[3];
  float bv = bias[n];
  __syncthreads();
#pragma unroll
  for (int mm = 0; mm < 16; ++mm) {
    const float* tr = &tS[mm * 16];
    float a = bv;
    a += tr[0] * b0.x + tr[1] * b0.y + tr[2] * b0.z + tr[3] * b0.w;
    a += tr[4] * b1.x + tr[5] * b1.y + tr[6] * b1.z + tr[7] * b1.w;
    a += tr[8] * b2.x + tr[9] * b2.y + tr[10] * b2.z + tr[11] * b2.w;
    a += tr[12] * b3.x + tr[13] * b3.y + tr[14] * b3.z + tr[15] * b3.w;
    out[(size_t)(mbase + mm) * OUT_F + n] = a;
  }
}

// ---------------------------------------------------------------------------
// finish (partial path): out = bias + lora + sum_kz partials. No atomics.
// ---------------------------------------------------------------------------
__global__ __launch_bounds__(256) void finish(const float* __restrict__ t,
                                              const float* __restrict__ lb,
                                              const float* __restrict__ bias,
                                              const float* __restrict__ part,
                                              float* __restrict__ out) {
  __shared__ float tS[16 * 16];
  int tid = threadIdx.x;
  int n = blockIdx.x * 256 + tid;
  int mbase = blockIdx.y * 16;
  if (tid < 64) ((float4*)tS)[tid] = ((const float4*)(t + (size_t)mbase * 16))[tid];
  const float4* lbp = (const float4*)(lb + (size_t)n * 16);
  float4 b0 = lbp[0], b1 = lbp[1], b2 = lbp[2], b3 = lbp[3];
  float bv = bias[n];
  __syncthreads();
#pragma unroll
  for (int mm = 0; mm < 16; ++mm) {
    const float* tr = &tS[mm * 16];
    float a = bv;
    a += tr[0] * b0.x + tr[1] * b0.y + tr[2] * b0.z + tr[3] * b0.w;
    a += tr[4] * b1.x + tr[5] * b1.y + tr[6] * b1.z + tr[7] * b1.w;
    a += tr[8] * b2.x + tr[9] * b2.y + tr[10] * b2.z + tr[11] * b2.w;
    a += tr[12] * b3.x + tr[13] * b3.y + tr[14] * b3.z + tr[15] * b3.w;
    size_t base = (size_t)(mbase + mm) * OUT_F + n;
#pragma unroll
    for (int kz = 0; kz < SPLITK; ++kz)
      a += part[(size_t)kz * TOKENS * OUT_F + base];
    out[base] = a;
  }
}

// ---------------------------------------------------------------------------
// gemm_q2: int8 MFMA, ZERO LDS, ZERO barriers in the K-loop.
// R8 post-mortem: every K-iter structure since R2 had a __syncthreads; the
// compiler emits s_waitcnt vmcnt(0) before s_barrier, so each iter drains all
// global loads and the block's waves lockstep on the slowest -> ~3900 stall
// cyc/iter regardless of prefetch depth (61-64 us invariant). Here B-frags
// come straight from global wq (4 words -> unpack4 -> i32x4), A-frags from
// global xq (L1-hot). B words ping-pong in parity registers loaded 2 slices
// ahead (~1300 cyc cover vs ~900 HBM); nothing ever force-drains them --
// the compiler's dependency-based s_waitcnt vmcnt(N) is the only wait.
// ---------------------------------------------------------------------------
__global__ __launch_bounds__(256, 2) void gemm_q2(const signed char* __restrict__ xq,
                                                  const int* __restrict__ wq,
                                                  const __half* __restrict__ nf,
                                                  const float* __restrict__ sx,
                                                  float* __restrict__ dst,
                                                  int mode) {
  int tid = threadIdx.x;
  int n0 = blockIdx.x * 128;
  int m0 = blockIdx.y * 128;
  int kz = blockIdx.z;
  int kbase = kz * KSPAN;

  int wave = tid >> 6, lane = tid & 63;
  int quad = lane >> 4, l15 = lane & 15;
  int mo = (wave & 1) * 64, no = (wave >> 1) * 64;

  // per-frag global base ptrs: 16 B at [row][kbase + kt*64 + quad*16]
  const signed char* gA[4];
  const signed char* gB[4];
#pragma unroll
  for (int i = 0; i < 4; ++i) {
    gA[i] = xq + (size_t)(m0 + mo + i * 16 + l15) * IN_F + kbase + quad * 16;
    gB[i] = (const signed char*)wq + (size_t)(n0 + no + i * 16 + l15) * IN_F + kbase + quad * 16;
  }
  // norms, transposed layout nf[g][n]; this lane's column base
  const __half* nfg = nf + (size_t)(kz * (KSPAN / 128)) * 8192 + n0 + no + l15;

  i32x4 zi = {0, 0, 0, 0};
  f32x4 zf = {0.f, 0.f, 0.f, 0.f};
  i32x4 acc[4][4];
  f32x4 accf[4][4];
#pragma unroll
  for (int i = 0; i < 4; ++i)
#pragma unroll
    for (int j = 0; j < 4; ++j) { acc[i][j] = zi; accf[i][j] = zf; }

  // B-word pipeline: parity buffers, 2 slices ahead
  uint4 wE[4], wO[4];
#pragma unroll
  for (int i = 0; i < 4; ++i) {
    wE[i] = *(const uint4*)(gB[i]);        // slice 0
    wO[i] = *(const uint4*)(gB[i] + 64);   // slice 1
  }
  float nC[4], nN[4];
#pragma unroll
  for (int i = 0; i < 4; ++i) nC[i] = __half2float(nfg[i * 16]) * (1.f / 3.f);

#pragma unroll 1
  for (int kt2 = 0; kt2 < KT / 2; ++kt2) {
    int kt = kt2 * 2;
    int koE = (kt + 2 < KT ? kt + 2 : KT - 2) * 64;  // clamped (tail values unused)
    int koO = (kt + 3 < KT ? kt + 3 : KT - 1) * 64;
    int g2 = (kt2 + 1 < KT / 2 ? kt2 + 1 : kt2);

    // ---- even slice kt: consume wE, refill wE with B(kt+2) ----
    {
      uint4 tW0 = *(const uint4*)(gB[0] + koE);
      uint4 tW1 = *(const uint4*)(gB[1] + koE);
      uint4 tW2 = *(const uint4*)(gB[2] + koE);
      uint4 tW3 = *(const uint4*)(gB[3] + koE);
      i32x4 aC[4];
#pragma unroll
      for (int i = 0; i < 4; ++i) aC[i] = *(const i32x4*)(gA[i] + kt * 64);
#pragma unroll
      for (int i = 0; i < 4; ++i)
        nN[i] = __half2float(nfg[(size_t)g2 * 8192 + i * 16]) * (1.f / 3.f);
      i32x4 bf[4];
#pragma unroll
      for (int i = 0; i < 4; ++i)
        bf[i] = (i32x4){(int)unpack4(wE[i].x), (int)unpack4(wE[i].y),
                        (int)unpack4(wE[i].z), (int)unpack4(wE[i].w)};
#pragma unroll
      for (int mt = 0; mt < 4; ++mt)
#pragma unroll
        for (int nt = 0; nt < 4; ++nt)
          acc[mt][nt] = __builtin_amdgcn_mfma_i32_16x16x64_i8(aC[mt], bf[nt], acc[mt][nt], 0, 0, 0);
      wE[0] = tW0; wE[1] = tW1; wE[2] = tW2; wE[3] = tW3;
    }

    // ---- odd slice kt+1: consume wO, refill wO with B(kt+3); group rescale --
    {
      uint4 tW0 = *(const uint4*)(gB[0] + koO);
      uint4 tW1 = *(const uint4*)(gB[1] + koO);
      uint4 tW2 = *(const uint4*)(gB[2] + koO);
      uint4 tW3 = *(const uint4*)(gB[3] + koO);
      i32x4 aC[4];
#pragma unroll
      for (int i = 0; i < 4; ++i) aC[i] = *(const i32x4*)(gA[i] + (kt + 1) * 64);
      i32x4 bf[4];
#pragma unroll
      for (int i = 0; i < 4; ++i)
        bf[i] = (i32x4){(int)unpack4(wO[i].x), (int)unpack4(wO[i].y),
                        (int)unpack4(wO[i].z), (int)unpack4(wO[i].w)};
#pragma unroll
      for (int mt = 0; mt < 4; ++mt)
#pragma unroll
        for (int nt = 0; nt < 4; ++nt)
          acc[mt][nt] = __builtin_amdgcn_mfma_i32_16x16x64_i8(aC[mt], bf[nt], acc[mt][nt], 0, 0, 0);
      wO[0] = tW0; wO[1] = tW1; wO[2] = tW2; wO[3] = tW3;
      // rescale group g = kz*16 + kt2 (128 k complete)
#pragma unroll
      for (int nt = 0; nt < 4; ++nt) {
        float s = nC[nt];
#pragma unroll
        for (int mt = 0; mt < 4; ++mt) {
#pragma unroll
          for (int r = 0; r < 4; ++r)
            accf[mt][nt][r] = fmaf((float)acc[mt][nt][r], s, accf[mt][nt][r]);
          acc[mt][nt] = zi;
        }
        nC[nt] = nN[nt];
      }
    }
  }

  // ---- epilogue: apply x scale (per m, half = kz>>1), write partials ----
  // C/D layout: row m = quad*4 + reg, col n = lane&15  [m89/m91 verified]
  const float* sxh = sx + (kz >> 1) * 256;
  if (mode) {
    float* pp = dst + (size_t)kz * TOKENS * OUT_F;
#pragma unroll
    for (int mt = 0; mt < 4; ++mt)
#pragma unroll
      for (int r = 0; r < 4; ++r) {
        int mm = m0 + mo + mt * 16 + quad * 4 + r;
        float s = sxh[mm];
#pragma unroll
        for (int nt = 0; nt < 4; ++nt) {
          int nn = n0 + no + nt * 16 + l15;
          pp[(size_t)mm * OUT_F + nn] = accf[mt][nt][r] * s;
        }
      }
  } else {
#pragma unroll
    for (int mt = 0; mt < 4; ++mt)
#pragma unroll
      for (int r = 0; r < 4; ++r) {
        int mm = m0 + mo + mt * 16 + quad * 4 + r;
        float s = sxh[mm];
#pragma unroll
        for (int nt = 0; nt < 4; ++nt) {
          int nn = n0 + no + nt * 16 + l15;
          atomicAdd(&dst[(size_t)mm * OUT_F + nn], accf[mt][nt][r] * s);
        }
      }
  }
}

extern "C" void kernel_launch(void* const* d_in, const int* in_sizes, int n_in,
                              void* d_out, int out_size, void* d_ws, size_t ws_size,
                              hipStream_t stream) {
  (void)in_sizes; (void)n_in; (void)out_size;
  const float* x = (const float*)d_in[0];
  const int* wq = (const int*)d_in[1];
  const void* wn_raw = d_in[2];
  const float* bias = (const float*)d_in[3];
  const float* la = (const float*)d_in[4];
  const float* lb = (const float*)d_in[5];
  float* out = (float*)d_out;

  signed char* xq = (signed char*)((char*)d_ws + XQ_OFF);
  float* t = (float*)((char*)d_ws + T_OFF);
  float* sx = (float*)((char*)d_ws + SX_OFF);
  __half* nf = (__half*)((char*)d_ws + NF_OFF);
  float* part = (float*)((char*)d_ws + PART_OFF);
  int usep = ws_size >= WS_NEED;  // constant per deployment -> graph-safe

  hipMemsetAsync(t, 0, (size_t)TOKENS * 16 * 4, stream);  // atomicAdd target
  prep<<<1088, 256, 0, stream>>>(wn_raw, nf, x, la, xq, sx, t);
  if (usep) {
    gemm_q2<<<dim3(OUT_F / 128, TOKENS / 128, SPLITK), 256, 0, stream>>>(xq, wq, nf, sx, part, 1);
    finish<<<dim3(OUT_F / 256, TOKENS / 16), 256, 0, stream>>>(t, lb, bias, part, out);
  } else {
    prep2<<<dim3(OUT_F / 256, TOKENS / 16), 256, 0, stream>>>(t, lb, bias, out);
    gemm_q2<<<dim3(OUT_F / 128, TOKENS / 128, SPLITK), 256, 0, stream>>>(xq, wq, nf, sx, out, 0);
  }
}